// Round 3
// baseline (408.130 us; speedup 1.0000x reference)
//
#include <hip/hip_runtime.h>
#include <cstdint>
#include <cstddef>

constexpr int B_ROWS = 128;
constexpr int N_COLS = 65536;
constexpr int CAP    = 4096;     // per-row candidate-list capacity (expected ~1.8k)

// ---- ws layout (bytes) ----
constexpr size_t OFF_HISTCNT = 0;                      // int[128][2048]   1MB
constexpr size_t OFF_CAND    = (size_t)1 << 20;        // uint[128][4096]  2MB (1MB..3MB)
constexpr size_t OFF_MISC    = (size_t)3 << 20;
constexpr size_t MO_NUMPOS   = 0;      // int[128]
constexpr size_t MO_SPOS     = 512;    // float[128]
constexpr size_t MO_ROWS     = 1024;   // double[128]
constexpr size_t MO_ROWDEN   = 2048;   // int[128]
constexpr size_t MO_CANDBIN  = 2560;   // int[128]
constexpr size_t MO_R1       = 3072;   // int[128]
constexpr size_t MO_KARR     = 3584;   // int[128]
constexpr size_t MO_CANDCNT  = 4096;   // int[128]
constexpr size_t MO_SABOVE   = 4608;   // float[128]
constexpr size_t MO_AUTO64   = 5120;   // ull[128]
constexpr size_t MISC_ZERO   = 6144;
constexpr size_t OFF_KEYS    = (size_t)4 << 20;        // uint[128*65536] 32MB (optional)

// ---- monotone key <-> pred ----
__device__ __forceinline__ unsigned key_from_pred(float x) {
  unsigned b = __float_as_uint(x);
  return (b & 0x80000000u) ? ~b : (b | 0x80000000u);
}
__device__ __forceinline__ float pred_from_key(unsigned k) {
  unsigned b = (k & 0x80000000u) ? (k ^ 0x80000000u) : ~k;
  return __uint_as_float(b);
}

// ---- elementwise losses (validated absmax=0.0 in R1) ----
__device__ __forceinline__ float neg_loss(float x) {
  float ax = fabsf(x);
  float e  = expf(-ax);
  float p  = (x >= 0.0f) ? 1.0f / (1.0f + e) : e / (1.0f + e);
  float sp = fmaxf(x, 0.0f) + log1pf(e);
  float f  = p;                     // 1 - p_t for label=0
  float l  = sp * f * f * 0.25f;
  return (p >= 0.5f) ? l * 3.0f : l;
}
__device__ __forceinline__ float pos_loss(float x) {
  float ax = fabsf(x);
  float e  = expf(-ax);
  float p  = (x >= 0.0f) ? 1.0f / (1.0f + e) : e / (1.0f + e);
  float sp = fmaxf(-x, 0.0f) + log1pf(e);
  float f  = 1.0f - p;
  float l  = sp * f * f * 0.75f;
  return (p < 0.5f) ? l * 3.0f : l;
}
__device__ __forceinline__ float loss_from_key(unsigned k) { return neg_loss(pred_from_key(k)); }

// ---- shared building blocks ----
__device__ void suffix_scan(int* c, float* l, int M) {
  const int T = blockDim.x;
  const int i0 = threadIdx.x, i1 = threadIdx.x + T;
  for (int d = 1; d < M; d <<= 1) {
    int vi0 = 0, vi1 = 0; float vf0 = 0.0f, vf1 = 0.0f;
    const bool h0 = i0 < M, h1 = i1 < M;
    if (h0) { vi0 = c[i0] + ((i0 + d < M) ? c[i0 + d] : 0);
              vf0 = l[i0] + ((i0 + d < M) ? l[i0 + d] : 0.0f); }
    if (h1) { vi1 = c[i1] + ((i1 + d < M) ? c[i1 + d] : 0);
              vf1 = l[i1] + ((i1 + d < M) ? l[i1 + d] : 0.0f); }
    __syncthreads();
    if (h0) { c[i0] = vi0; l[i0] = vf0; }
    if (h1) { c[i1] = vi1; l[i1] = vf1; }
    __syncthreads();
  }
}
__device__ void suffix_scan_i(int* c, int M) {
  const int T = blockDim.x;
  const int i0 = threadIdx.x, i1 = threadIdx.x + T;
  for (int d = 1; d < M; d <<= 1) {
    int v0 = 0, v1 = 0;
    const bool h0 = i0 < M, h1 = i1 < M;
    if (h0) v0 = c[i0] + ((i0 + d < M) ? c[i0 + d] : 0);
    if (h1) v1 = c[i1] + ((i1 + d < M) ? c[i1 + d] : 0);
    __syncthreads();
    if (h0) c[i0] = v0;
    if (h1) c[i1] = v1;
    __syncthreads();
  }
}
// max b in [0,M) with scanned[b] >= r
__device__ int find_cut(const int* sc, int M, int r, int* ctrl) {
  __syncthreads();
  if (threadIdx.x == 0) *ctrl = -1;
  __syncthreads();
  int loc = -1;
  for (int i = threadIdx.x; i < M; i += blockDim.x)
    if (sc[i] >= r) loc = i;
  if (loc >= 0) atomicMax(ctrl, loc);
  __syncthreads();
  return *ctrl;
}

// =======================  K1: count-hist + keys + pos stats  =======================
constexpr int K1_TPB = 256;
constexpr int K1_SEGS = 8;
constexpr int K1_SEG_ELEMS = N_COLS / K1_SEGS;         // 8192
constexpr int K1_ITERS = K1_SEG_ELEMS / (K1_TPB * 4);  // 8

template <bool STORE_KEYS>
__global__ __launch_bounds__(K1_TPB)
void k1_hist(const float* __restrict__ pred, const float* __restrict__ label,
             int* __restrict__ histCnt, int* __restrict__ numPos, float* __restrict__ SPos,
             unsigned* __restrict__ keys)
{
  __shared__ int   hcnt[2048];
  __shared__ int   wnp[K1_TPB / 64];
  __shared__ float wsp[K1_TPB / 64];
  const int tid = threadIdx.x;
  for (int i = tid; i < 2048; i += K1_TPB) hcnt[i] = 0;
  __syncthreads();

  const int row = blockIdx.x / K1_SEGS;
  const int seg = blockIdx.x % K1_SEGS;
  const size_t base = (size_t)row * N_COLS + (size_t)seg * K1_SEG_ELEMS;
  const float4* p4 = reinterpret_cast<const float4*>(pred + base);
  const float4* l4 = reinterpret_cast<const float4*>(label + base);
  uint4* k4 = STORE_KEYS ? reinterpret_cast<uint4*>(keys + base) : nullptr;

  int npos = 0; float spos = 0.0f;
  for (int it = 0; it < K1_ITERS; ++it) {
    const int vi = it * K1_TPB + tid;
    const float4 pv = p4[vi];
    const float4 lv = l4[vi];
    const float xs[4] = {pv.x, pv.y, pv.z, pv.w};
    const float ys[4] = {lv.x, lv.y, lv.z, lv.w};
    unsigned ks[4];
#pragma unroll
    for (int j = 0; j < 4; ++j) {
      const float x = xs[j];
      if (ys[j] > 0.5f) {
        npos += 1;
        spos += pos_loss(x);
        ks[j] = 0u;
      } else {
        const unsigned key = key_from_pred(x);
        ks[j] = key;
        atomicAdd(&hcnt[key >> 21], 1);
      }
    }
    if (STORE_KEYS) { uint4 uk; uk.x = ks[0]; uk.y = ks[1]; uk.z = ks[2]; uk.w = ks[3]; k4[vi] = uk; }
  }

#pragma unroll
  for (int off = 32; off > 0; off >>= 1) {
    npos += __shfl_down(npos, off);
    spos += __shfl_down(spos, off);
  }
  const int wid = tid >> 6, lane = tid & 63;
  if (lane == 0) { wnp[wid] = npos; wsp[wid] = spos; }
  __syncthreads();
  if (tid == 0) {
    int tn = 0; float ts = 0.0f;
    for (int i = 0; i < K1_TPB / 64; ++i) { tn += wnp[i]; ts += wsp[i]; }
    atomicAdd(&numPos[row], tn);
    unsafeAtomicAdd(&SPos[row], ts);
  }
  __syncthreads();
  for (int i = tid; i < 2048; i += K1_TPB)
    if (hcnt[i]) atomicAdd(&histCnt[row * 2048 + i], hcnt[i]);
}

// =======================  K2a: per-row coarse cutoff  =======================
__global__ __launch_bounds__(1024)
void k2a_cut(const int* __restrict__ histCnt, const int* __restrict__ numPos,
             int* __restrict__ candBin, unsigned long long* __restrict__ auto64,
             int* __restrict__ r1Arr, int* __restrict__ kArr)
{
  __shared__ int s_cnt[2048];
  __shared__ int s_ctrl;
  const int tid = threadIdx.x, row = blockIdx.x;
  const int np = numPos[row];
  const int nneg = N_COLS - np;
  const int k = (3 * np < nneg) ? 3 * np : nneg;
  for (int i = tid; i < 2048; i += 1024) s_cnt[i] = histCnt[row * 2048 + i];
  __syncthreads();
  suffix_scan_i(s_cnt, 2048);
  if (k <= 0) {
    if (tid == 0) {
      candBin[row] = -1; auto64[row] = 1ull << 32; r1Arr[row] = 0; kArr[row] = k;
    }
    return;
  }
  const int b1 = find_cut(s_cnt, 2048, k, &s_ctrl);
  if (tid == 0) {
    const int above = (b1 + 1 < 2048) ? s_cnt[b1 + 1] : 0;
    candBin[row] = b1;
    auto64[row]  = (unsigned long long)(b1 + 1) << 21;
    r1Arr[row]   = k - above;
    kArr[row]    = k;
  }
}

// =======================  K2b: parallel auto-loss + candidate gather  =======================
constexpr int K2B_TPB = 256;
constexpr int K2B_SEGS = 16;
constexpr int K2B_SEG_ELEMS = N_COLS / K2B_SEGS;           // 4096
constexpr int K2B_ITERS = K2B_SEG_ELEMS / (K2B_TPB * 4);   // 4

template <bool USE_KEYS>
__global__ __launch_bounds__(K2B_TPB)
void k2b_stream(const float* __restrict__ pred, const float* __restrict__ label,
                const unsigned* __restrict__ keys,
                const int* __restrict__ candBin, const unsigned long long* __restrict__ auto64,
                unsigned* __restrict__ candList, int* __restrict__ candCnt,
                float* __restrict__ S_above)
{
  const int tid = threadIdx.x;
  const int row = blockIdx.x / K2B_SEGS;
  const int seg = blockIdx.x % K2B_SEGS;
  const size_t base = (size_t)row * N_COLS + (size_t)seg * K2B_SEG_ELEMS;
  const int cb = candBin[row];
  const unsigned long long at = auto64[row];
  const int lane = tid & 63, wid = tid >> 6;

  float acc = 0.0f;
  for (int it = 0; it < K2B_ITERS; ++it) {
    unsigned ks[4];
    if (USE_KEYS) {
      const uint4 kv = reinterpret_cast<const uint4*>(keys + base)[it * K2B_TPB + tid];
      ks[0] = kv.x; ks[1] = kv.y; ks[2] = kv.z; ks[3] = kv.w;
    } else {
      const float4 pv = reinterpret_cast<const float4*>(pred + base)[it * K2B_TPB + tid];
      const float4 lv = reinterpret_cast<const float4*>(label + base)[it * K2B_TPB + tid];
      const float xs[4] = {pv.x, pv.y, pv.z, pv.w};
      const float ys[4] = {lv.x, lv.y, lv.z, lv.w};
#pragma unroll
      for (int j = 0; j < 4; ++j) ks[j] = (ys[j] > 0.5f) ? 0u : key_from_pred(xs[j]);
    }
#pragma unroll
    for (int j = 0; j < 4; ++j) {
      const unsigned key = ks[j];
      const bool isneg = key != 0u;
      const bool autosel = isneg && ((unsigned long long)key >= at);
      if (autosel) acc += loss_from_key(key);
      const bool cand = isneg && !autosel && ((int)(key >> 21) == cb);
      const unsigned long long m = __ballot(cand);
      if (m) {
        const int leader = __ffsll((long long)m) - 1;
        int bidx = 0;
        if (lane == leader) bidx = atomicAdd(&candCnt[row], (int)__popcll(m));
        bidx = __shfl(bidx, leader, 64);
        if (cand) {
          const int p = (int)__popcll(m & ((1ull << lane) - 1ull));
          const int idx = bidx + p;
          if (idx < CAP) candList[(size_t)row * CAP + idx] = key;
        }
      }
    }
  }

#pragma unroll
  for (int off = 32; off > 0; off >>= 1) acc += __shfl_down(acc, off);
  __shared__ float wacc[K2B_TPB / 64];
  if (lane == 0) wacc[wid] = acc;
  __syncthreads();
  if (tid == 0) {
    float t = 0.0f;
    for (int i = 0; i < K2B_TPB / 64; ++i) t += wacc[i];
    unsafeAtomicAdd(&S_above[row], t);
  }
}

// fallback streamer (only if candidate list overflowed)
template <bool USE_KEYS>
__device__ void stream_bin(const float* __restrict__ pred, const float* __restrict__ label,
                           const unsigned* __restrict__ keys, int row, int b1, int b2,
                           int* hcnt, float* hloss)
{
  const size_t base = (size_t)row * N_COLS;
  const int tid = threadIdx.x;
  for (int it = 0; it < N_COLS / (1024 * 4); ++it) {
    unsigned ks[4];
    if (USE_KEYS) {
      const uint4 kv = reinterpret_cast<const uint4*>(keys + base)[it * 1024 + tid];
      ks[0] = kv.x; ks[1] = kv.y; ks[2] = kv.z; ks[3] = kv.w;
    } else {
      const float4 pv = reinterpret_cast<const float4*>(pred + base)[it * 1024 + tid];
      const float4 lv = reinterpret_cast<const float4*>(label + base)[it * 1024 + tid];
      const float xs[4] = {pv.x, pv.y, pv.z, pv.w};
      const float ys[4] = {lv.x, lv.y, lv.z, lv.w};
#pragma unroll
      for (int j = 0; j < 4; ++j) ks[j] = (ys[j] > 0.5f) ? 0u : key_from_pred(xs[j]);
    }
#pragma unroll
    for (int j = 0; j < 4; ++j) {
      const unsigned key = ks[j];
      if (!key) continue;
      if ((int)(key >> 21) != b1) continue;
      if (b2 < 0) {
        const int b = (key >> 10) & 0x7FF;
        atomicAdd(&hcnt[b], 1);
        atomicAdd(&hloss[b], loss_from_key(key));
      } else {
        if ((int)((key >> 10) & 0x7FF) != b2) continue;
        const int b = key & 0x3FF;
        atomicAdd(&hcnt[b], 1);
        atomicAdd(&hloss[b], loss_from_key(key));
      }
    }
  }
}

// =======================  K2c: per-row in-LDS refine  =======================
template <bool USE_KEYS>
__global__ __launch_bounds__(1024)
void k2c_refine(const float* __restrict__ pred, const float* __restrict__ label,
                const unsigned* __restrict__ keys,
                const int* __restrict__ numPos, const float* __restrict__ SPos,
                const int* __restrict__ candBin, const int* __restrict__ r1Arr,
                const int* __restrict__ kArr, const int* __restrict__ candCnt,
                const unsigned* __restrict__ candList, const float* __restrict__ S_above,
                double* __restrict__ rowS, int* __restrict__ rowDen)
{
  __shared__ unsigned s_key[CAP];
  __shared__ float    s_lv[CAP];
  __shared__ int      h_cnt[2048];
  __shared__ float    h_loss[2048];
  __shared__ int      r3cnt[1024];
  __shared__ float    r3loss[1024];
  __shared__ int      s_ctrl;

  const int tid = threadIdx.x, row = blockIdx.x;
  const int np = numPos[row];
  const int k  = kArr[row];
  if (k <= 0) {
    if (tid == 0) { rowS[row] = (double)SPos[row]; rowDen[row] = np; }
    return;
  }
  const int r1 = r1Arr[row];
  const int b1 = candBin[row];
  const int cc = candCnt[row];
  float S = 0.0f;

  for (int i = tid; i < 2048; i += 1024) { h_cnt[i] = 0; h_loss[i] = 0.0f; }
  __syncthreads();

  int b2, r2;
  if (cc <= CAP) {
    for (int i = tid; i < cc; i += 1024) {
      const unsigned key = candList[(size_t)row * CAP + i];
      const float l = loss_from_key(key);
      s_key[i] = key; s_lv[i] = l;
      const int b = (key >> 10) & 0x7FF;
      atomicAdd(&h_cnt[b], 1);
      atomicAdd(&h_loss[b], l);
    }
    __syncthreads();
    suffix_scan(h_cnt, h_loss, 2048);
    b2 = find_cut(h_cnt, 2048, r1, &s_ctrl);
    r2 = r1 - ((b2 + 1 < 2048) ? h_cnt[b2 + 1] : 0);
    S += (b2 + 1 < 2048) ? h_loss[b2 + 1] : 0.0f;
    __syncthreads();

    for (int i = tid; i < 1024; i += 1024) { r3cnt[i] = 0; r3loss[i] = 0.0f; }
    __syncthreads();
    for (int i = tid; i < cc; i += 1024) {
      const unsigned key = s_key[i];
      if ((int)((key >> 10) & 0x7FF) == b2) {
        atomicAdd(&r3cnt[key & 0x3FF], 1);
        atomicAdd(&r3loss[key & 0x3FF], s_lv[i]);
      }
    }
    __syncthreads();
  } else {
    // overflow fallback: streamed level-2
    stream_bin<USE_KEYS>(pred, label, keys, row, b1, -1, h_cnt, h_loss);
    __syncthreads();
    suffix_scan(h_cnt, h_loss, 2048);
    b2 = find_cut(h_cnt, 2048, r1, &s_ctrl);
    r2 = r1 - ((b2 + 1 < 2048) ? h_cnt[b2 + 1] : 0);
    S += (b2 + 1 < 2048) ? h_loss[b2 + 1] : 0.0f;
    __syncthreads();
    for (int i = tid; i < 1024; i += 1024) { r3cnt[i] = 0; r3loss[i] = 0.0f; }
    __syncthreads();
    stream_bin<USE_KEYS>(pred, label, keys, row, b1, b2, r3cnt, r3loss);
    __syncthreads();
  }

  // level 3: exact key bins
  for (int i = tid; i < 1024; i += 1024) { h_cnt[i] = r3cnt[i]; h_loss[i] = r3loss[i]; }
  __syncthreads();
  suffix_scan(h_cnt, h_loss, 1024);
  const int b3 = find_cut(h_cnt, 1024, r2, &s_ctrl);
  const int r3 = r2 - ((b3 + 1 < 1024) ? h_cnt[b3 + 1] : 0);
  S += (b3 + 1 < 1024) ? h_loss[b3 + 1] : 0.0f;
  S += (float)r3 * (r3loss[b3] / (float)r3cnt[b3]);   // exact-key ties

  if (tid == 0) {
    rowS[row] = (double)S + (double)S_above[row] + (double)SPos[row];
    rowDen[row] = np + k;
  }
}

// =======================  K3: final reduction  =======================
__global__ __launch_bounds__(B_ROWS)
void k3_final(const double* __restrict__ rowS, const int* __restrict__ rowDen,
              float* __restrict__ out)
{
  __shared__ double sd[B_ROWS];
  __shared__ long long si[B_ROWS];
  const int t = threadIdx.x;
  sd[t] = rowS[t];
  si[t] = (long long)rowDen[t];
  __syncthreads();
  if (t == 0) {
    double s = 0.0; long long d = 0;
    for (int i = 0; i < B_ROWS; ++i) { s += sd[i]; d += si[i]; }
    out[0] = (float)(s / (double)d);
  }
}

// =======================  host launcher  =======================
extern "C" void kernel_launch(void* const* d_in, const int* in_sizes, int n_in,
                              void* d_out, int out_size, void* d_ws, size_t ws_size,
                              hipStream_t stream)
{
  const float* pred  = (const float*)d_in[0];
  const float* label = (const float*)d_in[1];
  float* out = (float*)d_out;
  char* ws = (char*)d_ws;

  int*      histCnt = (int*)(ws + OFF_HISTCNT);
  unsigned* cand    = (unsigned*)(ws + OFF_CAND);
  char*     misc    = ws + OFF_MISC;
  int*      numPos  = (int*)(misc + MO_NUMPOS);
  float*    SPos    = (float*)(misc + MO_SPOS);
  double*   rowS    = (double*)(misc + MO_ROWS);
  int*      rowDen  = (int*)(misc + MO_ROWDEN);
  int*      candBin = (int*)(misc + MO_CANDBIN);
  int*      r1Arr   = (int*)(misc + MO_R1);
  int*      kArr    = (int*)(misc + MO_KARR);
  int*      candCnt = (int*)(misc + MO_CANDCNT);
  float*    S_above = (float*)(misc + MO_SABOVE);
  unsigned long long* auto64 = (unsigned long long*)(misc + MO_AUTO64);
  unsigned* keys    = (unsigned*)(ws + OFF_KEYS);

  const bool useKeys = ws_size >= OFF_KEYS + (size_t)B_ROWS * N_COLS * sizeof(unsigned);

  hipMemsetAsync(ws + OFF_HISTCNT, 0, (size_t)1 << 20, stream);
  hipMemsetAsync(ws + OFF_MISC, 0, MISC_ZERO, stream);

  const dim3 g1(B_ROWS * K1_SEGS), t1(K1_TPB);
  const dim3 g2a(B_ROWS), t2a(1024);
  const dim3 g2b(B_ROWS * K2B_SEGS), t2b(K2B_TPB);
  const dim3 g2c(B_ROWS), t2c(1024);

  if (useKeys) {
    k1_hist<true><<<g1, t1, 0, stream>>>(pred, label, histCnt, numPos, SPos, keys);
    k2a_cut<<<g2a, t2a, 0, stream>>>(histCnt, numPos, candBin, auto64, r1Arr, kArr);
    k2b_stream<true><<<g2b, t2b, 0, stream>>>(pred, label, keys, candBin, auto64, cand, candCnt, S_above);
    k2c_refine<true><<<g2c, t2c, 0, stream>>>(pred, label, keys, numPos, SPos, candBin, r1Arr, kArr,
                                              candCnt, cand, S_above, rowS, rowDen);
  } else {
    k1_hist<false><<<g1, t1, 0, stream>>>(pred, label, histCnt, numPos, SPos, nullptr);
    k2a_cut<<<g2a, t2a, 0, stream>>>(histCnt, numPos, candBin, auto64, r1Arr, kArr);
    k2b_stream<false><<<g2b, t2b, 0, stream>>>(pred, label, nullptr, candBin, auto64, cand, candCnt, S_above);
    k2c_refine<false><<<g2c, t2c, 0, stream>>>(pred, label, nullptr, numPos, SPos, candBin, r1Arr, kArr,
                                               candCnt, cand, S_above, rowS, rowDen);
  }
  k3_final<<<dim3(1), dim3(B_ROWS), 0, stream>>>(rowS, rowDen, out);
}

// Round 5
// 175.837 us; speedup vs baseline: 2.3211x; 2.3211x over previous
//
#include <hip/hip_runtime.h>
#include <cstdint>
#include <cstddef>

constexpr int B_ROWS = 128;
constexpr int N_COLS = 65536;
constexpr int CAP    = 4096;     // per-row candidate-list capacity (expected ~1.8k)

// ---- ws layout (bytes) ----
constexpr size_t OFF_HISTCNT = 0;                      // int[128][2048]   1MB
constexpr size_t OFF_CAND    = (size_t)1 << 20;        // uint[128][4096]  2MB (1MB..3MB)
constexpr size_t OFF_MISC    = (size_t)3 << 20;
constexpr size_t MO_NUMPOS   = 0;      // int[128]
constexpr size_t MO_SPOS     = 512;    // float[128]
constexpr size_t MO_ROWS     = 1024;   // double[128]
constexpr size_t MO_ROWDEN   = 2048;   // int[128]
constexpr size_t MO_CANDBIN  = 2560;   // int[128]
constexpr size_t MO_R1       = 3072;   // int[128]
constexpr size_t MO_KARR     = 3584;   // int[128]
constexpr size_t MO_CANDCNT  = 4096;   // int[128]
constexpr size_t MO_SABOVE   = 4608;   // float[128]
constexpr size_t MO_AUTO64   = 5120;   // ull[128]
constexpr size_t MISC_ZERO   = 6144;
constexpr size_t OFF_KEYS    = (size_t)4 << 20;        // uint[128*65536] 32MB (optional)

// ---- monotone key <-> pred ----
__device__ __forceinline__ unsigned key_from_pred(float x) {
  unsigned b = __float_as_uint(x);
  return (b & 0x80000000u) ? ~b : (b | 0x80000000u);
}
__device__ __forceinline__ float pred_from_key(unsigned k) {
  unsigned b = (k & 0x80000000u) ? (k ^ 0x80000000u) : ~k;
  return __uint_as_float(b);
}

// ---- elementwise losses (validated absmax=0.0 in R1/R3) ----
__device__ __forceinline__ float neg_loss(float x) {
  float ax = fabsf(x);
  float e  = expf(-ax);
  float p  = (x >= 0.0f) ? 1.0f / (1.0f + e) : e / (1.0f + e);
  float sp = fmaxf(x, 0.0f) + log1pf(e);
  float f  = p;                     // 1 - p_t for label=0
  float l  = sp * f * f * 0.25f;
  return (p >= 0.5f) ? l * 3.0f : l;
}
__device__ __forceinline__ float pos_loss(float x) {
  float ax = fabsf(x);
  float e  = expf(-ax);
  float p  = (x >= 0.0f) ? 1.0f / (1.0f + e) : e / (1.0f + e);
  float sp = fmaxf(-x, 0.0f) + log1pf(e);
  float f  = 1.0f - p;
  float l  = sp * f * f * 0.75f;
  return (p < 0.5f) ? l * 3.0f : l;
}
__device__ __forceinline__ float loss_from_key(unsigned k) { return neg_loss(pred_from_key(k)); }

// ---- shared building blocks ----
__device__ void suffix_scan(int* c, float* l, int M) {
  const int T = blockDim.x;
  const int i0 = threadIdx.x, i1 = threadIdx.x + T;
  for (int d = 1; d < M; d <<= 1) {
    int vi0 = 0, vi1 = 0; float vf0 = 0.0f, vf1 = 0.0f;
    const bool h0 = i0 < M, h1 = i1 < M;
    if (h0) { vi0 = c[i0] + ((i0 + d < M) ? c[i0 + d] : 0);
              vf0 = l[i0] + ((i0 + d < M) ? l[i0 + d] : 0.0f); }
    if (h1) { vi1 = c[i1] + ((i1 + d < M) ? c[i1 + d] : 0);
              vf1 = l[i1] + ((i1 + d < M) ? l[i1 + d] : 0.0f); }
    __syncthreads();
    if (h0) { c[i0] = vi0; l[i0] = vf0; }
    if (h1) { c[i1] = vi1; l[i1] = vf1; }
    __syncthreads();
  }
}
__device__ void suffix_scan_i(int* c, int M) {
  const int T = blockDim.x;
  const int i0 = threadIdx.x, i1 = threadIdx.x + T;
  for (int d = 1; d < M; d <<= 1) {
    int v0 = 0, v1 = 0;
    const bool h0 = i0 < M, h1 = i1 < M;
    if (h0) v0 = c[i0] + ((i0 + d < M) ? c[i0 + d] : 0);
    if (h1) v1 = c[i1] + ((i1 + d < M) ? c[i1 + d] : 0);
    __syncthreads();
    if (h0) c[i0] = v0;
    if (h1) c[i1] = v1;
    __syncthreads();
  }
}
// max b in [0,M) with scanned[b] >= r
__device__ int find_cut(const int* sc, int M, int r, int* ctrl) {
  __syncthreads();
  if (threadIdx.x == 0) *ctrl = -1;
  __syncthreads();
  int loc = -1;
  for (int i = threadIdx.x; i < M; i += blockDim.x)
    if (sc[i] >= r) loc = i;
  if (loc >= 0) atomicMax(ctrl, loc);
  __syncthreads();
  return *ctrl;
}

// =======================  K1: count-hist + keys + pos stats  =======================
constexpr int K1_TPB = 256;
constexpr int K1_SEGS = 8;
constexpr int K1_SEG_ELEMS = N_COLS / K1_SEGS;         // 8192
constexpr int K1_ITERS = K1_SEG_ELEMS / (K1_TPB * 4);  // 8

template <bool STORE_KEYS>
__global__ __launch_bounds__(K1_TPB)
void k1_hist(const float* __restrict__ pred, const float* __restrict__ label,
             int* __restrict__ histCnt, int* __restrict__ numPos, float* __restrict__ SPos,
             unsigned* __restrict__ keys)
{
  __shared__ int   hcnt[2048];
  __shared__ int   wnp[K1_TPB / 64];
  __shared__ float wsp[K1_TPB / 64];
  const int tid = threadIdx.x;
  for (int i = tid; i < 2048; i += K1_TPB) hcnt[i] = 0;
  __syncthreads();

  const int row = blockIdx.x / K1_SEGS;
  const int seg = blockIdx.x % K1_SEGS;
  const size_t base = (size_t)row * N_COLS + (size_t)seg * K1_SEG_ELEMS;
  const float4* p4 = reinterpret_cast<const float4*>(pred + base);
  const float4* l4 = reinterpret_cast<const float4*>(label + base);
  uint4* k4 = STORE_KEYS ? reinterpret_cast<uint4*>(keys + base) : nullptr;

  int npos = 0; float spos = 0.0f;
  for (int it = 0; it < K1_ITERS; ++it) {
    const int vi = it * K1_TPB + tid;
    const float4 pv = p4[vi];
    const float4 lv = l4[vi];
    const float xs[4] = {pv.x, pv.y, pv.z, pv.w};
    const float ys[4] = {lv.x, lv.y, lv.z, lv.w};
    unsigned ks[4];
#pragma unroll
    for (int j = 0; j < 4; ++j) {
      const float x = xs[j];
      if (ys[j] > 0.5f) {
        npos += 1;
        spos += pos_loss(x);
        ks[j] = 0u;
      } else {
        const unsigned key = key_from_pred(x);
        ks[j] = key;
        atomicAdd(&hcnt[key >> 21], 1);
      }
    }
    if (STORE_KEYS) { uint4 uk; uk.x = ks[0]; uk.y = ks[1]; uk.z = ks[2]; uk.w = ks[3]; k4[vi] = uk; }
  }

#pragma unroll
  for (int off = 32; off > 0; off >>= 1) {
    npos += __shfl_down(npos, off);
    spos += __shfl_down(spos, off);
  }
  const int wid = tid >> 6, lane = tid & 63;
  if (lane == 0) { wnp[wid] = npos; wsp[wid] = spos; }
  __syncthreads();
  if (tid == 0) {
    int tn = 0; float ts = 0.0f;
    for (int i = 0; i < K1_TPB / 64; ++i) { tn += wnp[i]; ts += wsp[i]; }
    atomicAdd(&numPos[row], tn);
    unsafeAtomicAdd(&SPos[row], ts);
  }
  __syncthreads();
  for (int i = tid; i < 2048; i += K1_TPB)
    if (hcnt[i]) atomicAdd(&histCnt[row * 2048 + i], hcnt[i]);
}

// =======================  K2a: per-row coarse cutoff  =======================
__global__ __launch_bounds__(1024)
void k2a_cut(const int* __restrict__ histCnt, const int* __restrict__ numPos,
             int* __restrict__ candBin, unsigned long long* __restrict__ auto64,
             int* __restrict__ r1Arr, int* __restrict__ kArr)
{
  __shared__ int s_cnt[2048];
  __shared__ int s_ctrl;
  const int tid = threadIdx.x, row = blockIdx.x;
  const int np = numPos[row];
  const int nneg = N_COLS - np;
  const int k = (3 * np < nneg) ? 3 * np : nneg;
  for (int i = tid; i < 2048; i += 1024) s_cnt[i] = histCnt[row * 2048 + i];
  __syncthreads();
  suffix_scan_i(s_cnt, 2048);
  if (k <= 0) {
    if (tid == 0) {
      candBin[row] = -1; auto64[row] = 1ull << 32; r1Arr[row] = 0; kArr[row] = k;
    }
    return;
  }
  const int b1 = find_cut(s_cnt, 2048, k, &s_ctrl);
  if (tid == 0) {
    const int above = (b1 + 1 < 2048) ? s_cnt[b1 + 1] : 0;
    candBin[row] = b1;
    auto64[row]  = (unsigned long long)(b1 + 1) << 21;
    r1Arr[row]   = k - above;
    kArr[row]    = k;
  }
}

// =======================  K2b: parallel auto-loss + LDS-staged candidate gather  ============
// R3 lesson: per-ballot global atomicAdd to candCnt[row] serialized the whole kernel
// (269us, VALUBusy 13%). Now: block-local LDS list + LDS counter, ONE global atomicAdd
// per block, then bulk copy to the block's reserved slice. 131k global atomics -> 2048.
constexpr int K2B_TPB = 256;
constexpr int K2B_SEGS = 16;
constexpr int K2B_SEG_ELEMS = N_COLS / K2B_SEGS;           // 4096
constexpr int K2B_ITERS = K2B_SEG_ELEMS / (K2B_TPB * 4);   // 4

template <bool USE_KEYS>
__global__ __launch_bounds__(K2B_TPB)
void k2b_stream(const float* __restrict__ pred, const float* __restrict__ label,
                const unsigned* __restrict__ keys,
                const int* __restrict__ candBin, const unsigned long long* __restrict__ auto64,
                unsigned* __restrict__ candList, int* __restrict__ candCnt,
                float* __restrict__ S_above)
{
  __shared__ unsigned s_cand[K2B_SEG_ELEMS];   // worst case: whole segment is candidates
  __shared__ int      s_cnt;
  __shared__ int      s_base;
  __shared__ float    wacc[K2B_TPB / 64];

  const int tid = threadIdx.x;
  const int row = blockIdx.x / K2B_SEGS;
  const int seg = blockIdx.x % K2B_SEGS;
  const size_t base = (size_t)row * N_COLS + (size_t)seg * K2B_SEG_ELEMS;
  const int cb = candBin[row];
  const unsigned long long at = auto64[row];
  const int lane = tid & 63, wid = tid >> 6;

  if (tid == 0) s_cnt = 0;
  __syncthreads();

  float acc = 0.0f;
  for (int it = 0; it < K2B_ITERS; ++it) {
    unsigned ks[4];
    if (USE_KEYS) {
      const uint4 kv = reinterpret_cast<const uint4*>(keys + base)[it * K2B_TPB + tid];
      ks[0] = kv.x; ks[1] = kv.y; ks[2] = kv.z; ks[3] = kv.w;
    } else {
      const float4 pv = reinterpret_cast<const float4*>(pred + base)[it * K2B_TPB + tid];
      const float4 lv = reinterpret_cast<const float4*>(label + base)[it * K2B_TPB + tid];
      const float xs[4] = {pv.x, pv.y, pv.z, pv.w};
      const float ys[4] = {lv.x, lv.y, lv.z, lv.w};
#pragma unroll
      for (int j = 0; j < 4; ++j) ks[j] = (ys[j] > 0.5f) ? 0u : key_from_pred(xs[j]);
    }
#pragma unroll
    for (int j = 0; j < 4; ++j) {
      const unsigned key = ks[j];
      if (key == 0u) continue;                       // positive
      if ((unsigned long long)key >= at) {           // auto-selected: above cand bin
        acc += loss_from_key(key);
      } else if ((int)(key >> 21) == cb) {           // candidate: stage in LDS
        const int idx = atomicAdd(&s_cnt, 1);        // LDS atomic: cheap
        s_cand[idx] = key;                           // idx < 4096 by construction
      }
    }
  }

  // reduce auto-selected loss: wave shuffle -> LDS -> one global float atomic per block
#pragma unroll
  for (int off = 32; off > 0; off >>= 1) acc += __shfl_down(acc, off);
  if (lane == 0) wacc[wid] = acc;
  __syncthreads();
  if (tid == 0) {
    float t = 0.0f;
    for (int i = 0; i < K2B_TPB / 64; ++i) t += wacc[i];
    unsafeAtomicAdd(&S_above[row], t);
    s_base = atomicAdd(&candCnt[row], s_cnt);        // ONE global atomic per block
  }
  __syncthreads();

  const int cnt = s_cnt, gbase = s_base;
  for (int i = tid; i < cnt; i += K2B_TPB) {
    const int g = gbase + i;
    if (g < CAP) candList[(size_t)row * CAP + g] = s_cand[i];
    // overflow entries dropped; candCnt still counts them -> k2c streams fallback
  }
}

// fallback streamer (only if candidate list overflowed)
template <bool USE_KEYS>
__device__ void stream_bin(const float* __restrict__ pred, const float* __restrict__ label,
                           const unsigned* __restrict__ keys, int row, int b1, int b2,
                           int* hcnt, float* hloss)
{
  const size_t base = (size_t)row * N_COLS;
  const int tid = threadIdx.x;
  for (int it = 0; it < N_COLS / (1024 * 4); ++it) {
    unsigned ks[4];
    if (USE_KEYS) {
      const uint4 kv = reinterpret_cast<const uint4*>(keys + base)[it * 1024 + tid];
      ks[0] = kv.x; ks[1] = kv.y; ks[2] = kv.z; ks[3] = kv.w;
    } else {
      const float4 pv = reinterpret_cast<const float4*>(pred + base)[it * 1024 + tid];
      const float4 lv = reinterpret_cast<const float4*>(label + base)[it * 1024 + tid];
      const float xs[4] = {pv.x, pv.y, pv.z, pv.w};
      const float ys[4] = {lv.x, lv.y, lv.z, lv.w};
#pragma unroll
      for (int j = 0; j < 4; ++j) ks[j] = (ys[j] > 0.5f) ? 0u : key_from_pred(xs[j]);
    }
#pragma unroll
    for (int j = 0; j < 4; ++j) {
      const unsigned key = ks[j];
      if (!key) continue;
      if ((int)(key >> 21) != b1) continue;
      if (b2 < 0) {
        const int b = (key >> 10) & 0x7FF;
        atomicAdd(&hcnt[b], 1);
        atomicAdd(&hloss[b], loss_from_key(key));
      } else {
        if ((int)((key >> 10) & 0x7FF) != b2) continue;
        const int b = key & 0x3FF;
        atomicAdd(&hcnt[b], 1);
        atomicAdd(&hloss[b], loss_from_key(key));
      }
    }
  }
}

// =======================  K2c: per-row in-LDS refine  =======================
template <bool USE_KEYS>
__global__ __launch_bounds__(1024)
void k2c_refine(const float* __restrict__ pred, const float* __restrict__ label,
                const unsigned* __restrict__ keys,
                const int* __restrict__ numPos, const float* __restrict__ SPos,
                const int* __restrict__ candBin, const int* __restrict__ r1Arr,
                const int* __restrict__ kArr, const int* __restrict__ candCnt,
                const unsigned* __restrict__ candList, const float* __restrict__ S_above,
                double* __restrict__ rowS, int* __restrict__ rowDen)
{
  __shared__ unsigned s_key[CAP];
  __shared__ float    s_lv[CAP];
  __shared__ int      h_cnt[2048];
  __shared__ float    h_loss[2048];
  __shared__ int      r3cnt[1024];
  __shared__ float    r3loss[1024];
  __shared__ int      s_ctrl;

  const int tid = threadIdx.x, row = blockIdx.x;
  const int np = numPos[row];
  const int k  = kArr[row];
  if (k <= 0) {
    if (tid == 0) { rowS[row] = (double)SPos[row]; rowDen[row] = np; }
    return;
  }
  const int r1 = r1Arr[row];
  const int b1 = candBin[row];
  const int cc = candCnt[row];
  float S = 0.0f;

  for (int i = tid; i < 2048; i += 1024) { h_cnt[i] = 0; h_loss[i] = 0.0f; }
  __syncthreads();

  int b2, r2;
  if (cc <= CAP) {
    for (int i = tid; i < cc; i += 1024) {
      const unsigned key = candList[(size_t)row * CAP + i];
      const float l = loss_from_key(key);
      s_key[i] = key; s_lv[i] = l;
      const int b = (key >> 10) & 0x7FF;
      atomicAdd(&h_cnt[b], 1);
      atomicAdd(&h_loss[b], l);
    }
    __syncthreads();
    suffix_scan(h_cnt, h_loss, 2048);
    b2 = find_cut(h_cnt, 2048, r1, &s_ctrl);
    r2 = r1 - ((b2 + 1 < 2048) ? h_cnt[b2 + 1] : 0);
    S += (b2 + 1 < 2048) ? h_loss[b2 + 1] : 0.0f;
    __syncthreads();

    for (int i = tid; i < 1024; i += 1024) { r3cnt[i] = 0; r3loss[i] = 0.0f; }
    __syncthreads();
    for (int i = tid; i < cc; i += 1024) {
      const unsigned key = s_key[i];
      if ((int)((key >> 10) & 0x7FF) == b2) {
        atomicAdd(&r3cnt[key & 0x3FF], 1);
        atomicAdd(&r3loss[key & 0x3FF], s_lv[i]);
      }
    }
    __syncthreads();
  } else {
    // overflow fallback: streamed level-2
    stream_bin<USE_KEYS>(pred, label, keys, row, b1, -1, h_cnt, h_loss);
    __syncthreads();
    suffix_scan(h_cnt, h_loss, 2048);
    b2 = find_cut(h_cnt, 2048, r1, &s_ctrl);
    r2 = r1 - ((b2 + 1 < 2048) ? h_cnt[b2 + 1] : 0);
    S += (b2 + 1 < 2048) ? h_loss[b2 + 1] : 0.0f;
    __syncthreads();
    for (int i = tid; i < 1024; i += 1024) { r3cnt[i] = 0; r3loss[i] = 0.0f; }
    __syncthreads();
    stream_bin<USE_KEYS>(pred, label, keys, row, b1, b2, r3cnt, r3loss);
    __syncthreads();
  }

  // level 3: exact key bins
  for (int i = tid; i < 1024; i += 1024) { h_cnt[i] = r3cnt[i]; h_loss[i] = r3loss[i]; }
  __syncthreads();
  suffix_scan(h_cnt, h_loss, 1024);
  const int b3 = find_cut(h_cnt, 1024, r2, &s_ctrl);
  const int r3 = r2 - ((b3 + 1 < 1024) ? h_cnt[b3 + 1] : 0);
  S += (b3 + 1 < 1024) ? h_loss[b3 + 1] : 0.0f;
  S += (float)r3 * (r3loss[b3] / (float)r3cnt[b3]);   // exact-key ties

  if (tid == 0) {
    rowS[row] = (double)S + (double)S_above[row] + (double)SPos[row];
    rowDen[row] = np + k;
  }
}

// =======================  K3: final reduction  =======================
__global__ __launch_bounds__(B_ROWS)
void k3_final(const double* __restrict__ rowS, const int* __restrict__ rowDen,
              float* __restrict__ out)
{
  __shared__ double sd[B_ROWS];
  __shared__ long long si[B_ROWS];
  const int t = threadIdx.x;
  sd[t] = rowS[t];
  si[t] = (long long)rowDen[t];
  __syncthreads();
  if (t == 0) {
    double s = 0.0; long long d = 0;
    for (int i = 0; i < B_ROWS; ++i) { s += sd[i]; d += si[i]; }
    out[0] = (float)(s / (double)d);
  }
}

// =======================  host launcher  =======================
extern "C" void kernel_launch(void* const* d_in, const int* in_sizes, int n_in,
                              void* d_out, int out_size, void* d_ws, size_t ws_size,
                              hipStream_t stream)
{
  const float* pred  = (const float*)d_in[0];
  const float* label = (const float*)d_in[1];
  float* out = (float*)d_out;
  char* ws = (char*)d_ws;

  int*      histCnt = (int*)(ws + OFF_HISTCNT);
  unsigned* cand    = (unsigned*)(ws + OFF_CAND);
  char*     misc    = ws + OFF_MISC;
  int*      numPos  = (int*)(misc + MO_NUMPOS);
  float*    SPos    = (float*)(misc + MO_SPOS);
  double*   rowS    = (double*)(misc + MO_ROWS);
  int*      rowDen  = (int*)(misc + MO_ROWDEN);
  int*      candBin = (int*)(misc + MO_CANDBIN);
  int*      r1Arr   = (int*)(misc + MO_R1);
  int*      kArr    = (int*)(misc + MO_KARR);
  int*      candCnt = (int*)(misc + MO_CANDCNT);
  float*    S_above = (float*)(misc + MO_SABOVE);
  unsigned long long* auto64 = (unsigned long long*)(misc + MO_AUTO64);
  unsigned* keys    = (unsigned*)(ws + OFF_KEYS);

  const bool useKeys = ws_size >= OFF_KEYS + (size_t)B_ROWS * N_COLS * sizeof(unsigned);

  hipMemsetAsync(ws + OFF_HISTCNT, 0, (size_t)1 << 20, stream);
  hipMemsetAsync(ws + OFF_MISC, 0, MISC_ZERO, stream);

  const dim3 g1(B_ROWS * K1_SEGS), t1(K1_TPB);
  const dim3 g2a(B_ROWS), t2a(1024);
  const dim3 g2b(B_ROWS * K2B_SEGS), t2b(K2B_TPB);
  const dim3 g2c(B_ROWS), t2c(1024);

  if (useKeys) {
    k1_hist<true><<<g1, t1, 0, stream>>>(pred, label, histCnt, numPos, SPos, keys);
    k2a_cut<<<g2a, t2a, 0, stream>>>(histCnt, numPos, candBin, auto64, r1Arr, kArr);
    k2b_stream<true><<<g2b, t2b, 0, stream>>>(pred, label, keys, candBin, auto64, cand, candCnt, S_above);
    k2c_refine<true><<<g2c, t2c, 0, stream>>>(pred, label, keys, numPos, SPos, candBin, r1Arr, kArr,
                                              candCnt, cand, S_above, rowS, rowDen);
  } else {
    k1_hist<false><<<g1, t1, 0, stream>>>(pred, label, histCnt, numPos, SPos, nullptr);
    k2a_cut<<<g2a, t2a, 0, stream>>>(histCnt, numPos, candBin, auto64, r1Arr, kArr);
    k2b_stream<false><<<g2b, t2b, 0, stream>>>(pred, label, nullptr, candBin, auto64, cand, candCnt, S_above);
    k2c_refine<false><<<g2c, t2c, 0, stream>>>(pred, label, nullptr, numPos, SPos, candBin, r1Arr, kArr,
                                               candCnt, cand, S_above, rowS, rowDen);
  }
  k3_final<<<dim3(1), dim3(B_ROWS), 0, stream>>>(rowS, rowDen, out);
}